// Round 8
// baseline (193.829 us; speedup 1.0000x reference)
//
#include <hip/hip_runtime.h>

#define BIGV 1e4f

constexpr int RH    = 8;     // output rows per wave
constexpr int NSLOT = 5;     // LDS ring slots per wave (rows)
constexpr int HALF  = 512;   // floats per half-row (per-wave x-strip)

typedef float f32x4 __attribute__((ext_vector_type(4)));   // native vec for nt-store

struct Row { float2 L; float4 M; float2 R; };   // cols gx-2 .. gx+5
struct Ero { float eL; float4 eM; float eR; };  // eroded cols gx-1 .. gx+4

#define WAITVM(n)  asm volatile("s_waitcnt vmcnt(" #n ")" ::: "memory")
#define WAITALL0() asm volatile("s_waitcnt vmcnt(0) lgkmcnt(0)" ::: "memory")
#define WAITLG0()  asm volatile("s_waitcnt lgkmcnt(0)" ::: "memory")
#define SCHED0()   __builtin_amdgcn_sched_barrier(0)

__device__ __forceinline__ float min3f(float a, float b, float c) { return fminf(fminf(a, b), c); }
__device__ __forceinline__ float max3f(float a, float b, float c) { return fmaxf(fmaxf(a, b), c); }

// async global->LDS DMA, 16B/lane; LDS dest = wave-uniform base + lane*16 (HW rule)
__device__ __forceinline__ void gld16(const void* g, void* l) {
    __builtin_amdgcn_global_load_lds(
        (const __attribute__((address_space(1))) void*)g,
        (__attribute__((address_space(3))) void*)l, 16, 0, 0);
}

// read one staged row from the ring into 2 chunk-Rows (interior halos direct from LDS;
// the wave-edge halo comes from the seam register or the image border constant)
__device__ __forceinline__ void read_row2(const float* wlds, int slot, int lx,
                                          int r, int H, bool isleft, float2 seam, Row* w) {
    if (r >= 0 && r < H) {                              // wave-uniform
        const float* sb = wlds + slot * HALF;
#pragma unroll
        for (int c = 0; c < 2; ++c) {
            const int fb = c * 256 + lx * 4;
            w[c].M = *(const float4*)(sb + fb);
            w[c].L = *(const float2*)(sb + fb - 2);     // lane0,c==0 reads guard pad (discarded)
            w[c].R = *(const float2*)(sb + fb + 4);     // lane63,c==1 reads next slot (discarded)
        }
        if (lx == 0)  w[0].L = isleft ? make_float2(BIGV, BIGV) : seam;  // px xoff-2,xoff-1
        if (lx == 63) w[1].R = isleft ? seam : make_float2(BIGV, BIGV);  // px xoff+512,+513
    } else {
#pragma unroll
        for (int c = 0; c < 2; ++c) {
            w[c].L = make_float2(BIGV, BIGV);
            w[c].M = make_float4(BIGV, BIGV, BIGV, BIGV);
            w[c].R = make_float2(BIGV, BIGV);
        }
    }
}

// compile-time indexed access (folds under full unroll) — generic path only
__device__ __forceinline__ float rget(const Row& r, int q) {
    switch (q) {
        case -2: return r.L.x; case -1: return r.L.y;
        case 0:  return r.M.x; case 1:  return r.M.y;
        case 2:  return r.M.z; case 3:  return r.M.w;
        case 4:  return r.R.x; default: return r.R.y;
    }
}
__device__ __forceinline__ float eget(const Ero& e, int q) {
    switch (q) {
        case -1: return e.eL;
        case 0:  return e.eM.x; case 1:  return e.eM.y;
        case 2:  return e.eM.z; case 3:  return e.eM.w;
        default: return e.eR;
    }
}

// ---- cross structuring element fast path: min over {C,N,S,W,E} ----
__device__ __forceinline__ Ero erode_cross(const Row& a, const Row& b, const Row& c,
                                           int r, int H, int gx, int W) {
    Ero e;
    if (r >= 0 && r < H) {                         // wave-uniform
        e.eL   = min3f(min3f(a.L.y, b.L.y, c.L.y), b.L.x, b.M.x);
        e.eM.x = min3f(min3f(a.M.x, b.M.x, c.M.x), b.L.y, b.M.y);
        e.eM.y = min3f(min3f(a.M.y, b.M.y, c.M.y), b.M.x, b.M.z);
        e.eM.z = min3f(min3f(a.M.z, b.M.z, c.M.z), b.M.y, b.M.w);
        e.eM.w = min3f(min3f(a.M.w, b.M.w, c.M.w), b.M.z, b.R.x);
        e.eR   = min3f(min3f(a.R.x, b.R.x, c.R.x), b.M.w, b.R.y);
        if (gx == 0)     e.eL = -BIGV;   // eroded col -1 is the dilation pad
        if (gx + 4 >= W) e.eR = -BIGV;   // eroded col W  is the dilation pad
    } else {
        e.eL = -BIGV; e.eM = make_float4(-BIGV, -BIGV, -BIGV, -BIGV); e.eR = -BIGV;
    }
    return e;
}

__device__ __forceinline__ float4 dilate_cross(const Ero& t, const Ero& m, const Ero& b) {
    float4 o;
    o.x = max3f(max3f(t.eM.x, m.eM.x, b.eM.x), m.eL,   m.eM.y);
    o.y = max3f(max3f(t.eM.y, m.eM.y, b.eM.y), m.eM.x, m.eM.z);
    o.z = max3f(max3f(t.eM.z, m.eM.z, b.eM.z), m.eM.y, m.eM.w);
    o.w = max3f(max3f(t.eM.w, m.eM.w, b.eM.w), m.eM.z, m.eR);
    return o;
}

// ---- generic runtime-mask fallback (uniform branch; not taken in this bench) ----
__device__ __forceinline__ Ero erode_gen(const Row& a, const Row& b, const Row& c,
                                         const bool* m, int r, int H, int gx, int W) {
    Ero e;
    if (r >= 0 && r < H) {
        float v[6];
#pragma unroll
        for (int p = 0; p < 6; ++p) {              // eroded column gx-1+p
            float acc = BIGV;
#pragma unroll
            for (int k = 0; k < 9; ++k) {
                const int di = k / 3, dj = k % 3;
                const Row& rr = (di == 0) ? a : ((di == 1) ? b : c);
                float t = rget(rr, p - 2 + dj);
                acc = fminf(acc, m[k] ? t : BIGV);
            }
            v[p] = acc;
        }
        e.eL = v[0]; e.eM.x = v[1]; e.eM.y = v[2]; e.eM.z = v[3]; e.eM.w = v[4]; e.eR = v[5];
        if (gx == 0)     e.eL = -BIGV;
        if (gx + 4 >= W) e.eR = -BIGV;
    } else {
        e.eL = -BIGV; e.eM = make_float4(-BIGV, -BIGV, -BIGV, -BIGV); e.eR = -BIGV;
    }
    return e;
}

__device__ __forceinline__ float4 dilate_gen(const Ero& e0, const Ero& e1, const Ero& e2,
                                             const bool* m) {
    float o[4];
#pragma unroll
    for (int j = 0; j < 4; ++j) {
        float acc = -BIGV;
#pragma unroll
        for (int k = 0; k < 9; ++k) {
            const int di = k / 3, dj = k % 3;
            const Ero& ee = (di == 0) ? e0 : ((di == 1) ? e1 : e2);
            acc = fmaxf(acc, m[k] ? eget(ee, j + dj - 1) : -BIGV);
        }
        o[j] = acc;
    }
    return make_float4(o[0], o[1], o[2], o[3]);
}

template <bool CROSS>
__device__ __forceinline__ void run(const float* __restrict__ img, float* __restrict__ out,
                                    float* wlds, const bool* m, int xoff, int y0,
                                    int lx, int H, int W, bool isleft) {
    const int seamoff = isleft ? HALF : HALF - 2;   // uniform addr of the 2-px seam halo
    float2 seam[NSLOT];                             // static-indexed register ring

    WAITALL0();                                     // clean vmcnt baseline
    SCHED0();
    // ---- prologue: stage rows y0-2..y0+2 -> slots 0..4 (3 vmem ops per group) ----
#pragma unroll
    for (int k = 0; k < NSLOT; ++k) {
        const int rc = min(max(y0 - 2 + k, 0), H - 1);
        const float* sp = img + (size_t)rc * W;
        gld16(sp + xoff + 4 * lx,       wlds + k * HALF);
        gld16(sp + xoff + 256 + 4 * lx, wlds + k * HALF + 256);
        seam[k] = *(const float2*)(sp + seamoff);
        SCHED0();
    }
    WAITVM(3);                                      // slots 0..3 landed (slot 4 in flight)
    SCHED0();
    Row B[2], C[2], Cur[2], Nxt[2];
    read_row2(wlds, 0, lx, y0 - 2, H, isleft, seam[0], B);
    read_row2(wlds, 1, lx, y0 - 1, H, isleft, seam[1], C);
    read_row2(wlds, 2, lx, y0,     H, isleft, seam[2], Cur);
    read_row2(wlds, 3, lx, y0 + 1, H, isleft, seam[3], Nxt);
    WAITLG0();                                      // reads drained before slot reuse
    SCHED0();
    // refill slots 0..2 with rows y0+3..y0+5
#pragma unroll
    for (int k = 0; k < 3; ++k) {
        const int rc = min(max(y0 + 3 + k, 0), H - 1);
        const float* sp = img + (size_t)rc * W;
        gld16(sp + xoff + 4 * lx,       wlds + k * HALF);
        gld16(sp + xoff + 256 + 4 * lx, wlds + k * HALF + 256);
        seam[k] = *(const float2*)(sp + seamoff);
        SCHED0();
    }
    Ero E0[2], E1[2];
#pragma unroll
    for (int c = 0; c < 2; ++c) {
        const int gx = xoff + c * 256 + lx * 4;
        E0[c] = CROSS ? erode_cross(B[c], C[c], Cur[c], y0 - 1, H, gx, W)
                      : erode_gen (B[c], C[c], Cur[c], m, y0 - 1, H, gx, W);
        E1[c] = CROSS ? erode_cross(C[c], Cur[c], Nxt[c], y0, H, gx, W)
                      : erode_gen (C[c], Cur[c], Nxt[c], m, y0, H, gx, W);
    }

    // ---- steady state. FIFO (3 ops/stage group, 2 nt-stores/iter) gives the exact
    // ladder K(i) = issued(i) - need(i) = {9,11,13,15,15,12,9,6} (re-derived, see journal)
#pragma unroll
    for (int i = 0; i < RH; ++i) {
        const int y = y0 + i;
        SCHED0();
        if      (i == 0) WAITVM(9);
        else if (i == 1) WAITVM(11);
        else if (i == 2) WAITVM(13);
        else if (i == 3) WAITVM(15);
        else if (i == 4) WAITVM(15);
        else if (i == 5) WAITVM(12);
        else if (i == 6) WAITVM(9);
        else             WAITVM(6);
        SCHED0();
        Row N[2];
        read_row2(wlds, (i + 4) % NSLOT, lx, y + 2, H, isleft, seam[(i + 4) % NSLOT], N);
#pragma unroll
        for (int c = 0; c < 2; ++c) {
            const int gx = xoff + c * 256 + lx * 4;
            Ero E2 = CROSS ? erode_cross(Cur[c], Nxt[c], N[c], y + 1, H, gx, W)
                           : erode_gen (Cur[c], Nxt[c], N[c], m, y + 1, H, gx, W);
            float4 o = CROSS ? dilate_cross(E0[c], E1[c], E2)
                             : dilate_gen (E0[c], E1[c], E2, m);
            f32x4 ov; ov.x = o.x; ov.y = o.y; ov.z = o.z; ov.w = o.w;
            __builtin_nontemporal_store(ov, (f32x4*)(out + (size_t)y * W + gx));
            E0[c] = E1[c]; E1[c] = E2;
            Cur[c] = Nxt[c]; Nxt[c] = N[c];
        }
        if (i < RH - 4) {                           // stage rows y0+6..y0+9 at i=0..3
            SCHED0();
            const int rc = min(max(y + 6, 0), H - 1);
            const float* sp = img + (size_t)rc * W;
            const int s = (i + 3) % NSLOT;
            gld16(sp + xoff + 4 * lx,       wlds + s * HALF);
            gld16(sp + xoff + 256 + 4 * lx, wlds + s * HALF + 256);
            seam[s] = *(const float2*)(sp + seamoff);
            SCHED0();
        }
    }
}

__global__ __launch_bounds__(128, 3) void opening_kernel(
    const float* __restrict__ img, const int* __restrict__ kern,
    float* __restrict__ out, int H, int W)
{
    // +2-float guard so read_row2's fb-2 access is always in-bounds on lane 0
    __shared__ float lds[2 * NSLOT * HALF + 2];   // ~20 KB -> 8 blocks/CU = 16 waves/CU
    const int lx   = threadIdx.x & 63;          // lane
    const int wid  = threadIdx.x >> 6;          // wave 0: left half, wave 1: right half
    const int xoff = wid * HALF;
    const int y0   = blockIdx.x * RH;
    const size_t pbase = (size_t)blockIdx.y * H * W;
    float* wlds = lds + 2 + wid * NSLOT * HALF; // waves fully independent: no barriers

    bool m[9];
#pragma unroll
    for (int k = 0; k < 9; ++k) m[k] = (kern[k] == 1);
    const bool cross = m[1] && m[3] && m[4] && m[5] && m[7] &&
                       !m[0] && !m[2] && !m[6] && !m[8];

    if (cross) run<true >(img + pbase, out + pbase, wlds, m, xoff, y0, lx, H, W, wid == 0);
    else       run<false>(img + pbase, out + pbase, wlds, m, xoff, y0, lx, H, W, wid == 0);
}

extern "C" void kernel_launch(void* const* d_in, const int* in_sizes, int n_in,
                              void* d_out, int out_size, void* d_ws, size_t ws_size,
                              hipStream_t stream) {
    const float* img  = (const float*)d_in[0];
    const int*   kern = (const int*)d_in[1];
    float*       out  = (float*)d_out;

    const int H = 1024, W = 1024;
    const int planes = in_sizes[0] / (H * W);   // B*C = 24

    dim3 block(128);                            // 2 independent waves per block
    dim3 grid(H / RH, planes);                  // (128, 24) = 3072 blocks
    opening_kernel<<<grid, block, 0, stream>>>(img, kern, out, H, W);
}

// Round 10
// 182.404 us; speedup vs baseline: 1.0626x; 1.0626x over previous
//
#include <hip/hip_runtime.h>

#define BIGV 1e4f

constexpr int RH = 8;   // output rows per thread
constexpr int TY = 4;   // waves per block (each wave = one y-group); block covers 32 rows

typedef float f32x4 __attribute__((ext_vector_type(4)));   // native vecs for nt load/store
typedef float f32x2 __attribute__((ext_vector_type(2)));

struct Raw { float4 M; float2 L; float2 R; };   // M: gx..gx+3 ; L/R only valid on edge lanes
struct Row { float2 L; float4 M; float2 R; };   // img columns gx-2 .. gx+5
struct Ero { float eL; float4 eM; float eR; };  // eroded columns gx-1 .. gx+4

__device__ __forceinline__ float min3f(float a, float b, float c) { return fminf(fminf(a, b), c); }
__device__ __forceinline__ float max3f(float a, float b, float c) { return fmaxf(fmaxf(a, b), c); }

// non-temporal loads: sets nt policy bits (evict-first / reduced L1 allocation).
// Theory: the ~1.45 TB/s read rate is capped by the per-CU L1 line-miss queue;
// nt changes the allocation path. (Read-side dual of the R5 nt-store.)
__device__ __forceinline__ float4 ntld4(const float* p) {
    f32x4 v = __builtin_nontemporal_load((const f32x4*)p);
    return make_float4(v.x, v.y, v.z, v.w);
}
__device__ __forceinline__ float2 ntld2(const float* p) {
    f32x2 v = __builtin_nontemporal_load((const f32x2*)p);
    return make_float2(v.x, v.y);
}

// raw load: one float4 per lane; halo float2 only on the wave's edge lanes (exec-masked)
__device__ __forceinline__ Raw load_raw(const float* __restrict__ img, int y, int gx,
                                        int lx, int H, int W) {
    Raw r;
    r.L = make_float2(BIGV, BIGV);
    r.R = make_float2(BIGV, BIGV);
    if (y >= 0 && y < H) {                         // wave-uniform (y uniform per wave)
        const float* q = img + (size_t)y * W;
        r.M = ntld4(q + gx);
        if (lx == 0  && gx > 0)     r.L = ntld2(q + gx - 2);
        if (lx == 63 && gx + 4 < W) r.R = ntld2(q + gx + 4);
    } else {
        r.M = make_float4(BIGV, BIGV, BIGV, BIGV);
    }
    return r;
}

// build full 8-wide row: interior halo from neighbor lanes via shuffle
__device__ __forceinline__ Row rowify(const Raw& r, int lx) {
    Row o;
    o.M = r.M;
    float lz = __shfl_up(r.M.z, 1, 64);    // lane-1's gx+2  -> my gx-2
    float lw = __shfl_up(r.M.w, 1, 64);    // lane-1's gx+3  -> my gx-1
    float rx = __shfl_down(r.M.x, 1, 64);  // lane+1's gx    -> my gx+4
    float ry = __shfl_down(r.M.y, 1, 64);  // lane+1's gx+1  -> my gx+5
    o.L = (lx == 0)  ? r.L : make_float2(lz, lw);
    o.R = (lx == 63) ? r.R : make_float2(rx, ry);
    return o;
}

// compile-time indexed access (folds under full unroll) — generic path only
__device__ __forceinline__ float rget(const Row& r, int q) {
    switch (q) {
        case -2: return r.L.x; case -1: return r.L.y;
        case 0:  return r.M.x; case 1:  return r.M.y;
        case 2:  return r.M.z; case 3:  return r.M.w;
        case 4:  return r.R.x; default: return r.R.y;
    }
}
__device__ __forceinline__ float eget(const Ero& e, int q) {
    switch (q) {
        case -1: return e.eL;
        case 0:  return e.eM.x; case 1:  return e.eM.y;
        case 2:  return e.eM.z; case 3:  return e.eM.w;
        default: return e.eR;
    }
}

// ---- cross structuring element fast path: min over {C,N,S,W,E} ----
__device__ __forceinline__ Ero erode_cross(const Row& a, const Row& b, const Row& c,
                                           int r, int H, int gx, int W) {
    Ero e;
    if (r >= 0 && r < H) {                         // wave-uniform
        e.eL   = min3f(min3f(a.L.y, b.L.y, c.L.y), b.L.x, b.M.x);
        e.eM.x = min3f(min3f(a.M.x, b.M.x, c.M.x), b.L.y, b.M.y);
        e.eM.y = min3f(min3f(a.M.y, b.M.y, c.M.y), b.M.x, b.M.z);
        e.eM.z = min3f(min3f(a.M.z, b.M.z, c.M.z), b.M.y, b.M.w);
        e.eM.w = min3f(min3f(a.M.w, b.M.w, c.M.w), b.M.z, b.R.x);
        e.eR   = min3f(min3f(a.R.x, b.R.x, c.R.x), b.M.w, b.R.y);
        if (gx == 0)     e.eL = -BIGV;   // eroded col -1 is the dilation pad
        if (gx + 4 >= W) e.eR = -BIGV;   // eroded col W  is the dilation pad
    } else {
        e.eL = -BIGV; e.eM = make_float4(-BIGV, -BIGV, -BIGV, -BIGV); e.eR = -BIGV;
    }
    return e;
}

__device__ __forceinline__ float4 dilate_cross(const Ero& t, const Ero& m, const Ero& b) {
    float4 o;
    o.x = max3f(max3f(t.eM.x, m.eM.x, b.eM.x), m.eL,   m.eM.y);
    o.y = max3f(max3f(t.eM.y, m.eM.y, b.eM.y), m.eM.x, m.eM.z);
    o.z = max3f(max3f(t.eM.z, m.eM.z, b.eM.z), m.eM.y, m.eM.w);
    o.w = max3f(max3f(t.eM.w, m.eM.w, b.eM.w), m.eM.z, m.eR);
    return o;
}

// ---- generic runtime-mask fallback (uniform branch; not taken in this bench) ----
__device__ __forceinline__ Ero erode_gen(const Row& a, const Row& b, const Row& c,
                                         const bool* m, int r, int H, int gx, int W) {
    Ero e;
    if (r >= 0 && r < H) {
        float v[6];
#pragma unroll
        for (int p = 0; p < 6; ++p) {              // eroded column gx-1+p
            float acc = BIGV;
#pragma unroll
            for (int k = 0; k < 9; ++k) {
                const int di = k / 3, dj = k % 3;
                const Row& rr = (di == 0) ? a : ((di == 1) ? b : c);
                float t = rget(rr, p - 2 + dj);
                acc = fminf(acc, m[k] ? t : BIGV);
            }
            v[p] = acc;
        }
        e.eL = v[0]; e.eM.x = v[1]; e.eM.y = v[2]; e.eM.z = v[3]; e.eM.w = v[4]; e.eR = v[5];
        if (gx == 0)     e.eL = -BIGV;
        if (gx + 4 >= W) e.eR = -BIGV;
    } else {
        e.eL = -BIGV; e.eM = make_float4(-BIGV, -BIGV, -BIGV, -BIGV); e.eR = -BIGV;
    }
    return e;
}

__device__ __forceinline__ float4 dilate_gen(const Ero& e0, const Ero& e1, const Ero& e2,
                                             const bool* m) {
    float o[4];
#pragma unroll
    for (int j = 0; j < 4; ++j) {
        float acc = -BIGV;
#pragma unroll
        for (int k = 0; k < 9; ++k) {
            const int di = k / 3, dj = k % 3;
            const Ero& ee = (di == 0) ? e0 : ((di == 1) ? e1 : e2);
            float t = eget(ee, j + dj - 1);
            acc = fmaxf(acc, m[k] ? t : -BIGV);
        }
        o[j] = acc;
    }
    return make_float4(o[0], o[1], o[2], o[3]);
}

template <bool CROSS>
__device__ __forceinline__ void run(const float* __restrict__ img, float* __restrict__ out,
                                    const bool* m, int gx, int y0, int lx, int H, int W) {
    // prologue: Rows y0-2..y0+1, Eros y0-1, y0
    Raw rb = load_raw(img, y0 - 2, gx, lx, H, W);
    Raw rc = load_raw(img, y0 - 1, gx, lx, H, W);
    Raw rd = load_raw(img, y0,     gx, lx, H, W);
    Raw re = load_raw(img, y0 + 1, gx, lx, H, W);
    Raw pref = load_raw(img, y0 + 2, gx, lx, H, W);   // prefetch for i=0

    Row B   = rowify(rb, lx);
    Row C   = rowify(rc, lx);
    Row Cur = rowify(rd, lx);   // Row(y0)
    Ero E0 = CROSS ? erode_cross(B, C, Cur, y0 - 1, H, gx, W)
                   : erode_gen(B, C, Cur, m, y0 - 1, H, gx, W);
    Row Nxt = rowify(re, lx);   // Row(y0+1)
    Ero E1 = CROSS ? erode_cross(C, Cur, Nxt, y0, H, gx, W)
                   : erode_gen(C, Cur, Nxt, m, y0, H, gx, W);

#pragma unroll
    for (int i = 0; i < RH; ++i) {
        const int y = y0 + i;
        Raw pref2 = pref;
        if (i < RH - 1)                               // compile-time under unroll
            pref2 = load_raw(img, y + 3, gx, lx, H, W);  // prefetch next iter's row
        Row N = rowify(pref, lx);                     // Row(y+2), loaded last iter
        Ero E2 = CROSS ? erode_cross(Cur, Nxt, N, y + 1, H, gx, W)
                       : erode_gen(Cur, Nxt, N, m, y + 1, H, gx, W);
        float4 o = CROSS ? dilate_cross(E0, E1, E2) : dilate_gen(E0, E1, E2, m);
        // NON-TEMPORAL store (R5: +5%): write stream doesn't allocate L2/LLC lines.
        f32x4 ov; ov.x = o.x; ov.y = o.y; ov.z = o.z; ov.w = o.w;
        __builtin_nontemporal_store(ov, (f32x4*)(out + (size_t)y * W + gx));
        Cur = Nxt; Nxt = N;
        E0 = E1; E1 = E2;
        pref = pref2;
    }
}

__global__ __launch_bounds__(256) void opening_kernel(
    const float* __restrict__ img, const int* __restrict__ kern,
    float* __restrict__ out, int H, int W)
{
    const int lx = threadIdx.x & 63;          // lane -> x strip
    const int ty = threadIdx.x >> 6;          // wave -> y group (wave-uniform)
    const int gx = blockIdx.x * 256 + lx * 4;
    const int y0 = (blockIdx.y * TY + ty) * RH;
    const size_t pbase = (size_t)blockIdx.z * H * W;

    bool m[9];
#pragma unroll
    for (int k = 0; k < 9; ++k) m[k] = (kern[k] == 1);

    const bool cross = m[1] && m[3] && m[4] && m[5] && m[7] &&
                       !m[0] && !m[2] && !m[6] && !m[8];

    if (cross) run<true >(img + pbase, out + pbase, m, gx, y0, lx, H, W);
    else       run<false>(img + pbase, out + pbase, m, gx, y0, lx, H, W);
}

extern "C" void kernel_launch(void* const* d_in, const int* in_sizes, int n_in,
                              void* d_out, int out_size, void* d_ws, size_t ws_size,
                              hipStream_t stream) {
    const float* img  = (const float*)d_in[0];
    const int*   kern = (const int*)d_in[1];
    float*       out  = (float*)d_out;

    const int H = 1024, W = 1024;
    const int planes = in_sizes[0] / (H * W);   // B*C = 24

    dim3 block(256);
    dim3 grid(W / 256, H / (TY * RH), planes);  // (4, 32, 24) = 3072 blocks
    opening_kernel<<<grid, block, 0, stream>>>(img, kern, out, H, W);
}